// Round 3
// baseline (103.517 us; speedup 1.0000x reference)
//
#include <hip/hip_runtime.h>
#include <math.h>

// Problem: B=16, N=512, F=256.
// Live computation only (attention matrix is dead code in the reference):
//   h       = x @ W_w^T + W_b                      [B,N,F]   (bf16 MFMA)
//   h_prime = leaky_relu(adj @ h, 0.2)             [B,N,F]   (sparse gather, h bf16)
//   g       = [x, h_prime] @ gate_w^T + gate_b     [B,N,1]
//   out     = sigmoid(g)*x + (1-sigmoid(g))*h_prime
//
// NOTE: measured dur includes ~90 us of harness reset (256 MB ws re-poison
// ~45 us + out fill + input restores + gaps) — confirmed by R6 rocprof: all
// top-5 dispatches are fillBufferAligned @ ~44 us / 256 MB. Controllable
// budget is the two kernels (~11-14 us).
// R7 (this round): k1 rewritten barrier-free — W-panel staged to LDS ONCE
// (32 KB bf16), A-fragments read DIRECTLY from global x in MFMA layout.
// Removes 7 of 8 __syncthreads (at 1 wave/SIMD each barrier is a full-CU
// stall with nothing to hide it) and all As LDS traffic. Numerically
// identical accumulation order to R5. + XCD swizzle so the 4 n-blocks
// sharing x-rows land on the same XCD L2.

#define BATCH 16
#define NNODE 512
#define FDIM  256
#define M_TOT (BATCH * NNODE)   // 8192

typedef __bf16 bf16x8 __attribute__((ext_vector_type(8)));
typedef __bf16 bf16x4 __attribute__((ext_vector_type(4)));
typedef float  f32x4  __attribute__((ext_vector_type(4)));

static __device__ __forceinline__ bf16x4 cvt4(float4 v) {
    bf16x4 r;
    r.x = (__bf16)v.x; r.y = (__bf16)v.y; r.z = (__bf16)v.z; r.w = (__bf16)v.w;
    return r;
}

static __device__ __forceinline__ bf16x8 cvt8(float4 lo, float4 hi) {
    bf16x8 r;
    r[0] = (__bf16)lo.x; r[1] = (__bf16)lo.y; r[2] = (__bf16)lo.z; r[3] = (__bf16)lo.w;
    r[4] = (__bf16)hi.x; r[5] = (__bf16)hi.y; r[6] = (__bf16)hi.z; r[7] = (__bf16)hi.w;
    return r;
}

// ---------------- Kernel 1: h = x @ W^T + bias  (bf16 MFMA) ----------------
// M=8192, N=256, K=256. BM=128, BN=64 -> 256 blocks (R2 geometry).
// Per block: stage W n-panel (64x256 -> 33.8 KB bf16 LDS) once, ONE barrier,
// then 8 fully-unrolled k-steps of {direct-global A loads + LDS B reads +
// 8 MFMA} with no further synchronization. A-load pattern per wave/k-step:
// 16 rows x 128 B contiguous (cache-line granular).
// BSTR=264 bf16 = 132 dwords == 4 mod 32 — same bank-residue as the
// measured conflict-free ASTR=72 layout.
#define BSTR 264

__global__ __launch_bounds__(256) void h_gemm_mfma(const float* __restrict__ x,
                                                   const float* __restrict__ W,
                                                   const float* __restrict__ bias,
                                                   __bf16* __restrict__ h) {
    __shared__ __bf16 Bs[64 * BSTR];   // 33792 B

    const int t    = threadIdx.x;
    const int wave = t >> 6;
    const int lane = t & 63;
    const int ln   = lane & 15;
    const int quad = lane >> 4;

    // XCD swizzle (8 XCDs, 256 blocks, bijective): each XCD owns 8 m-tiles
    // x 4 n-tiles, so the 4 blocks re-reading the same x rows share one L2.
    const int xcd = (int)(blockIdx.x & 7);
    const int idx = (int)(blockIdx.x >> 3);        // 0..31
    const int m0  = (xcd * 8 + (idx >> 2)) * 128;
    const int n0  = (idx & 3) * 64;

    // ---- One-time stage of W panel rows n0..n0+63, all K, f32 -> bf16 ----
    {
        const int r = t >> 2;                       // 0..63
        const int q = t & 3;                        // col quarter (64 cols)
        const float* wp = W + (size_t)(n0 + r) * FDIM + q * 64;
        __bf16* dst = &Bs[r * BSTR + q * 64];
#pragma unroll
        for (int i = 0; i < 16; i++) {
            float4 v = *(const float4*)(wp + 4 * i);
            *(bf16x4*)(dst + 4 * i) = cvt4(v);
        }
    }
    __syncthreads();   // the ONLY barrier

    // A rows owned by this wave (MFMA A-layout: lane ln -> row, quad -> k*8).
    const int rowA0 = m0 + wave * 32 + ln;
    const int rowA1 = rowA0 + 16;
    const float* xa0 = x + (size_t)rowA0 * FDIM + quad * 8;
    const float* xa1 = x + (size_t)rowA1 * FDIM + quad * 8;

    f32x4 acc[2][4] = {};

#pragma unroll
    for (int ks = 0; ks < FDIM; ks += 32) {
        float4 a0l = *(const float4*)(xa0 + ks);
        float4 a0h = *(const float4*)(xa0 + ks + 4);
        float4 a1l = *(const float4*)(xa1 + ks);
        float4 a1h = *(const float4*)(xa1 + ks + 4);
        bf16x8 a0 = cvt8(a0l, a0h);
        bf16x8 a1 = cvt8(a1l, a1h);

        const int kb = ks + quad * 8;
        bf16x8 b0 = *(const bf16x8*)&Bs[(0  + ln) * BSTR + kb];
        bf16x8 b1 = *(const bf16x8*)&Bs[(16 + ln) * BSTR + kb];
        bf16x8 b2 = *(const bf16x8*)&Bs[(32 + ln) * BSTR + kb];
        bf16x8 b3 = *(const bf16x8*)&Bs[(48 + ln) * BSTR + kb];

        acc[0][0] = __builtin_amdgcn_mfma_f32_16x16x32_bf16(a0, b0, acc[0][0], 0, 0, 0);
        acc[0][1] = __builtin_amdgcn_mfma_f32_16x16x32_bf16(a0, b1, acc[0][1], 0, 0, 0);
        acc[0][2] = __builtin_amdgcn_mfma_f32_16x16x32_bf16(a0, b2, acc[0][2], 0, 0, 0);
        acc[0][3] = __builtin_amdgcn_mfma_f32_16x16x32_bf16(a0, b3, acc[0][3], 0, 0, 0);
        acc[1][0] = __builtin_amdgcn_mfma_f32_16x16x32_bf16(a1, b0, acc[1][0], 0, 0, 0);
        acc[1][1] = __builtin_amdgcn_mfma_f32_16x16x32_bf16(a1, b1, acc[1][1], 0, 0, 0);
        acc[1][2] = __builtin_amdgcn_mfma_f32_16x16x32_bf16(a1, b2, acc[1][2], 0, 0, 0);
        acc[1][3] = __builtin_amdgcn_mfma_f32_16x16x32_bf16(a1, b3, acc[1][3], 0, 0, 0);
    }

    // Epilogue: D[row][col], col = lane&15, row = quad*4 + reg. Add bias, store bf16.
#pragma unroll
    for (int i = 0; i < 2; i++) {
        const int mbase = m0 + wave * 32 + (i ? 16 : 0) + quad * 4;
#pragma unroll
        for (int j = 0; j < 4; j++) {
            const int gn = n0 + j * 16 + ln;
            const float bv = bias[gn];
            f32x4 c = acc[i][j];
#pragma unroll
            for (int r = 0; r < 4; r++) {
                h[(size_t)(mbase + r) * FDIM + gn] = (__bf16)(c[r] + bv);
            }
        }
    }
}

// ---------------- Kernel 2: sparse aggregate + gate + blend ----------------
// One block (256 threads = 4 waves) per output row (b,i). adj ~5% dense binary.
// Wave w handles neighbors p = w, w+4, ...; each lane owns 4 consecutive
// bf16 columns (8B/lane loads). Cross-wave partials via LDS.
// At its latency/BW floor (~5-7 us): R2 unroll and R3 restructure both neutral.
// R5: no coeff broadcast barrier — every thread computes the sigmoid.
__global__ __launch_bounds__(256) void agg_gate(const float* __restrict__ adj,
                                                const float* __restrict__ x,
                                                const __bf16* __restrict__ h,
                                                const float* __restrict__ gw,
                                                const float* __restrict__ gb,
                                                float* __restrict__ out) {
    __shared__ int   lst[NNODE];
    __shared__ int   cnt;
    __shared__ float pSum[4][FDIM];
    __shared__ float red[4];

    const int t  = threadIdx.x;
    const int w  = t >> 6;
    const int l  = t & 63;
    const int bi = blockIdx.x;      // 0..8191
    const int b  = bi >> 9;

    if (t == 0) cnt = 0;
    __syncthreads();

    // Compact nonzero column indices of adj row into LDS.
    const float* arow2 = adj + (size_t)bi * NNODE;
    float2 av = *(const float2*)(arow2 + 2 * t);
    if (av.x != 0.0f) { int p = atomicAdd(&cnt, 1); lst[p] = 2 * t; }
    if (av.y != 0.0f) { int p = atomicAdd(&cnt, 1); lst[p] = 2 * t + 1; }

    const float xv = x[(size_t)bi * FDIM + t];   // overlap with compaction
    __syncthreads();

    const int n = cnt;
    const __bf16* hb = h + (size_t)b * NNODE * FDIM;

    // Neighbor-parallel gather: wave w takes p = w, w+4, ..., 2x unrolled.
    float4 s0 = {0.f, 0.f, 0.f, 0.f}, s1 = {0.f, 0.f, 0.f, 0.f};
    int p = w;
    for (; p + 4 < n; p += 8) {
        int j0 = lst[p];
        int j1 = lst[p + 4];
        bf16x4 v0 = *(const bf16x4*)(hb + (size_t)j0 * FDIM + 4 * l);
        bf16x4 v1 = *(const bf16x4*)(hb + (size_t)j1 * FDIM + 4 * l);
        s0.x += (float)v0.x; s0.y += (float)v0.y; s0.z += (float)v0.z; s0.w += (float)v0.w;
        s1.x += (float)v1.x; s1.y += (float)v1.y; s1.z += (float)v1.z; s1.w += (float)v1.w;
    }
    if (p < n) {
        int j0 = lst[p];
        bf16x4 v0 = *(const bf16x4*)(hb + (size_t)j0 * FDIM + 4 * l);
        s0.x += (float)v0.x; s0.y += (float)v0.y; s0.z += (float)v0.z; s0.w += (float)v0.w;
    }
    float4 s;
    s.x = s0.x + s1.x; s.y = s0.y + s1.y; s.z = s0.z + s1.z; s.w = s0.w + s1.w;
    *(float4*)&pSum[w][4 * l] = s;
    __syncthreads();

    // Thread t owns column t from here on.
    float sum = pSum[0][t] + pSum[1][t] + pSum[2][t] + pSum[3][t];
    float hp  = (sum > 0.0f) ? sum : 0.2f * sum;   // leaky_relu 0.2

    // gate: g = x . gw[0:256] + hp . gw[256:512] + gb
    float partial = xv * gw[t] + hp * gw[FDIM + t];
#pragma unroll
    for (int off = 32; off > 0; off >>= 1) partial += __shfl_down(partial, off);
    if (l == 0) red[w] = partial;
    __syncthreads();

    // All threads compute the scalar gate redundantly (no 2nd barrier).
    float g = red[0] + red[1] + red[2] + red[3] + gb[0];
    float c = 1.0f / (1.0f + expf(-g));
    out[(size_t)bi * FDIM + t] = c * xv + (1.0f - c) * hp;
}

extern "C" void kernel_launch(void* const* d_in, const int* in_sizes, int n_in,
                              void* d_out, int out_size, void* d_ws, size_t ws_size,
                              hipStream_t stream) {
    const float* x    = (const float*)d_in[0];
    const float* adj  = (const float*)d_in[1];
    const float* W_w  = (const float*)d_in[2];
    const float* W_b  = (const float*)d_in[3];
    // d_in[4] = A  (dead code in reference, unused)
    const float* gw   = (const float*)d_in[5];
    const float* gb   = (const float*)d_in[6];
    float* out = (float*)d_out;
    __bf16* h = (__bf16*)d_ws;   // 8192*256 bf16 = 4 MB scratch

    h_gemm_mfma<<<dim3(256), dim3(256), 0, stream>>>(x, W_w, W_b, h);
    agg_gate<<<dim3(M_TOT), dim3(256), 0, stream>>>(adj, x, h, gw, gb, out);
}

// Round 4
// 103.168 us; speedup vs baseline: 1.0034x; 1.0034x over previous
//
#include <hip/hip_runtime.h>
#include <math.h>

// Problem: B=16, N=512, F=256.
// Live computation only (attention matrix is dead code in the reference):
//   h       = x @ W_w^T + W_b                      [B,N,F]   (bf16 MFMA)
//   h_prime = leaky_relu(adj @ h, 0.2)             [B,N,F]   (sparse gather, h bf16)
//   g       = [x, h_prime] @ gate_w^T + gate_b     [B,N,1]
//   out     = sigmoid(g)*x + (1-sigmoid(g))*h_prime
//
// Measurement model (R6/R7 rocprof): total dur includes ~90 us harness reset
// (multiple 256 MB fillBufferAligned @ 44-47 us + input restores). Harness
// fill noise is +-2-3 us run-to-run — deltas below ~2 us are unattributable
// through the total. Controllable budget: the two kernels, ~11-14 us.
// R7: k1 barrier-free (W staged once, A direct-from-global, XCD swizzle) —
// indistinguishable from R5 through fill noise; kept (structurally cleaner).
// R8 (this round): k2 rewritten wave-per-row — no LDS, no barriers, no
// atomics. Ballot-based nonzero scan (wave-uniform masks -> scalar ctz loop,
// uniform gather addresses), lane owns 4 cols, shfl_xor butterfly for the
// gate dot. 2048 blocks x 4 independent waves = 32 waves/CU row parallelism
// (was 8 blocks/CU with 4 barriers each). Theory: k2 is latency/sync-bound
// (inputs L3-resident after harness restore), not at the naive HBM floor.

#define BATCH 16
#define NNODE 512
#define FDIM  256
#define M_TOT (BATCH * NNODE)   // 8192

typedef __bf16 bf16x8 __attribute__((ext_vector_type(8)));
typedef __bf16 bf16x4 __attribute__((ext_vector_type(4)));
typedef float  f32x4  __attribute__((ext_vector_type(4)));

static __device__ __forceinline__ bf16x4 cvt4(float4 v) {
    bf16x4 r;
    r.x = (__bf16)v.x; r.y = (__bf16)v.y; r.z = (__bf16)v.z; r.w = (__bf16)v.w;
    return r;
}

static __device__ __forceinline__ bf16x8 cvt8(float4 lo, float4 hi) {
    bf16x8 r;
    r[0] = (__bf16)lo.x; r[1] = (__bf16)lo.y; r[2] = (__bf16)lo.z; r[3] = (__bf16)lo.w;
    r[4] = (__bf16)hi.x; r[5] = (__bf16)hi.y; r[6] = (__bf16)hi.z; r[7] = (__bf16)hi.w;
    return r;
}

// ---------------- Kernel 1: h = x @ W^T + bias  (bf16 MFMA) ----------------
// M=8192, N=256, K=256. BM=128, BN=64 -> 256 blocks. Stage W n-panel once
// (33.8 KB bf16 LDS), ONE barrier, then 8 fully-unrolled k-steps of
// {direct-global A loads + LDS B reads + 8 MFMA}, no further sync.
// BSTR=264 bf16 = 132 dwords == 4 mod 32 — same bank-residue as the
// measured conflict-free ASTR=72 layout.
#define BSTR 264

__global__ __launch_bounds__(256) void h_gemm_mfma(const float* __restrict__ x,
                                                   const float* __restrict__ W,
                                                   const float* __restrict__ bias,
                                                   __bf16* __restrict__ h) {
    __shared__ __bf16 Bs[64 * BSTR];   // 33792 B

    const int t    = threadIdx.x;
    const int wave = t >> 6;
    const int lane = t & 63;
    const int ln   = lane & 15;
    const int quad = lane >> 4;

    // XCD swizzle (8 XCDs, 256 blocks, bijective): each XCD owns 8 m-tiles
    // x 4 n-tiles, so the 4 blocks re-reading the same x rows share one L2.
    const int xcd = (int)(blockIdx.x & 7);
    const int idx = (int)(blockIdx.x >> 3);        // 0..31
    const int m0  = (xcd * 8 + (idx >> 2)) * 128;
    const int n0  = (idx & 3) * 64;

    // ---- One-time stage of W panel rows n0..n0+63, all K, f32 -> bf16 ----
    {
        const int r = t >> 2;                       // 0..63
        const int q = t & 3;                        // col quarter (64 cols)
        const float* wp = W + (size_t)(n0 + r) * FDIM + q * 64;
        __bf16* dst = &Bs[r * BSTR + q * 64];
#pragma unroll
        for (int i = 0; i < 16; i++) {
            float4 v = *(const float4*)(wp + 4 * i);
            *(bf16x4*)(dst + 4 * i) = cvt4(v);
        }
    }
    __syncthreads();   // the ONLY barrier

    // A rows owned by this wave (MFMA A-layout: lane ln -> row, quad -> k*8).
    const int rowA0 = m0 + wave * 32 + ln;
    const int rowA1 = rowA0 + 16;
    const float* xa0 = x + (size_t)rowA0 * FDIM + quad * 8;
    const float* xa1 = x + (size_t)rowA1 * FDIM + quad * 8;

    f32x4 acc[2][4] = {};

#pragma unroll
    for (int ks = 0; ks < FDIM; ks += 32) {
        float4 a0l = *(const float4*)(xa0 + ks);
        float4 a0h = *(const float4*)(xa0 + ks + 4);
        float4 a1l = *(const float4*)(xa1 + ks);
        float4 a1h = *(const float4*)(xa1 + ks + 4);
        bf16x8 a0 = cvt8(a0l, a0h);
        bf16x8 a1 = cvt8(a1l, a1h);

        const int kb = ks + quad * 8;
        bf16x8 b0 = *(const bf16x8*)&Bs[(0  + ln) * BSTR + kb];
        bf16x8 b1 = *(const bf16x8*)&Bs[(16 + ln) * BSTR + kb];
        bf16x8 b2 = *(const bf16x8*)&Bs[(32 + ln) * BSTR + kb];
        bf16x8 b3 = *(const bf16x8*)&Bs[(48 + ln) * BSTR + kb];

        acc[0][0] = __builtin_amdgcn_mfma_f32_16x16x32_bf16(a0, b0, acc[0][0], 0, 0, 0);
        acc[0][1] = __builtin_amdgcn_mfma_f32_16x16x32_bf16(a0, b1, acc[0][1], 0, 0, 0);
        acc[0][2] = __builtin_amdgcn_mfma_f32_16x16x32_bf16(a0, b2, acc[0][2], 0, 0, 0);
        acc[0][3] = __builtin_amdgcn_mfma_f32_16x16x32_bf16(a0, b3, acc[0][3], 0, 0, 0);
        acc[1][0] = __builtin_amdgcn_mfma_f32_16x16x32_bf16(a1, b0, acc[1][0], 0, 0, 0);
        acc[1][1] = __builtin_amdgcn_mfma_f32_16x16x32_bf16(a1, b1, acc[1][1], 0, 0, 0);
        acc[1][2] = __builtin_amdgcn_mfma_f32_16x16x32_bf16(a1, b2, acc[1][2], 0, 0, 0);
        acc[1][3] = __builtin_amdgcn_mfma_f32_16x16x32_bf16(a1, b3, acc[1][3], 0, 0, 0);
    }

    // Epilogue: D[row][col], col = lane&15, row = quad*4 + reg. Add bias, store bf16.
#pragma unroll
    for (int i = 0; i < 2; i++) {
        const int mbase = m0 + wave * 32 + (i ? 16 : 0) + quad * 4;
#pragma unroll
        for (int j = 0; j < 4; j++) {
            const int gn = n0 + j * 16 + ln;
            const float bv = bias[gn];
            f32x4 c = acc[i][j];
#pragma unroll
            for (int r = 0; r < 4; r++) {
                h[(size_t)(mbase + r) * FDIM + gn] = (__bf16)(c[r] + bv);
            }
        }
    }
}

// ---------------- Kernel 2: sparse aggregate + gate + blend ----------------
// R8: one WAVE per output row (b,i); 2048 blocks x 256 thr = 4 independent
// waves/block. No LDS, no __syncthreads, no atomics.
// Per wave: lane l owns cols 4l..4l+3.
//  1. adj row: 4x float2 per lane (coalesced 512 B/round).
//  2. nonzeros via __ballot -> wave-uniform 64-bit masks; ctz bit-scan gives
//     wave-uniform j -> scalar-addressed coalesced 512 B gather of h[j].
//  3. f32 accumulate, leaky_relu, gate partial over own 4 cols,
//     shfl_xor butterfly (all lanes get g), sigmoid, float4 store.
__global__ __launch_bounds__(256) void agg_gate(const float* __restrict__ adj,
                                                const float* __restrict__ x,
                                                const __bf16* __restrict__ h,
                                                const float* __restrict__ gw,
                                                const float* __restrict__ gb,
                                                float* __restrict__ out) {
    const int t  = threadIdx.x;
    const int w  = t >> 6;
    const int l  = t & 63;
    const int bi = (int)blockIdx.x * 4 + w;   // 0..8191
    const int b  = bi >> 9;

    // Load adj row: entries r*128 + 2l, 2l+1 for r = 0..3.
    const float* arow = adj + (size_t)bi * NNODE;
    float2 a0 = *(const float2*)(arow + 0 * 128 + 2 * l);
    float2 a1 = *(const float2*)(arow + 1 * 128 + 2 * l);
    float2 a2 = *(const float2*)(arow + 2 * 128 + 2 * l);
    float2 a3 = *(const float2*)(arow + 3 * 128 + 2 * l);

    const float4 xv = *(const float4*)(x + (size_t)bi * FDIM + 4 * l);

    // Wave-uniform neighbor masks (even/odd slots per round).
    unsigned long long me[4], mo[4];
    me[0] = __ballot(a0.x != 0.0f); mo[0] = __ballot(a0.y != 0.0f);
    me[1] = __ballot(a1.x != 0.0f); mo[1] = __ballot(a1.y != 0.0f);
    me[2] = __ballot(a2.x != 0.0f); mo[2] = __ballot(a2.y != 0.0f);
    me[3] = __ballot(a3.x != 0.0f); mo[3] = __ballot(a3.y != 0.0f);

    const __bf16* hb = h + (size_t)b * NNODE * FDIM + 4 * l;  // lane's 4 cols

    float4 s = {0.f, 0.f, 0.f, 0.f};
#pragma unroll
    for (int r = 0; r < 4; r++) {
        unsigned long long m0 = me[r];
        while (m0) {
            const int bp = __builtin_ctzll(m0); m0 &= m0 - 1;
            const int j  = r * 128 + 2 * bp;          // wave-uniform
            bf16x4 v = *(const bf16x4*)(hb + (size_t)j * FDIM);
            s.x += (float)v.x; s.y += (float)v.y; s.z += (float)v.z; s.w += (float)v.w;
        }
        unsigned long long m1 = mo[r];
        while (m1) {
            const int bp = __builtin_ctzll(m1); m1 &= m1 - 1;
            const int j  = r * 128 + 2 * bp + 1;      // wave-uniform
            bf16x4 v = *(const bf16x4*)(hb + (size_t)j * FDIM);
            s.x += (float)v.x; s.y += (float)v.y; s.z += (float)v.z; s.w += (float)v.w;
        }
    }

    // leaky_relu(0.2)
    float4 hp;
    hp.x = (s.x > 0.0f) ? s.x : 0.2f * s.x;
    hp.y = (s.y > 0.0f) ? s.y : 0.2f * s.y;
    hp.z = (s.z > 0.0f) ? s.z : 0.2f * s.z;
    hp.w = (s.w > 0.0f) ? s.w : 0.2f * s.w;

    // gate: g = x . gw[0:256] + hp . gw[256:512] + gb (per-lane 4-col partial)
    const float4 g0 = *(const float4*)(gw + 4 * l);
    const float4 g1 = *(const float4*)(gw + FDIM + 4 * l);
    float partial = xv.x * g0.x + xv.y * g0.y + xv.z * g0.z + xv.w * g0.w
                  + hp.x * g1.x + hp.y * g1.y + hp.z * g1.z + hp.w * g1.w;
#pragma unroll
    for (int off = 32; off > 0; off >>= 1) partial += __shfl_xor(partial, off);

    const float g = partial + gb[0];
    const float c = 1.0f / (1.0f + expf(-g));

    float4 res;
    res.x = c * xv.x + (1.0f - c) * hp.x;
    res.y = c * xv.y + (1.0f - c) * hp.y;
    res.z = c * xv.z + (1.0f - c) * hp.z;
    res.w = c * xv.w + (1.0f - c) * hp.w;
    *(float4*)(out + (size_t)bi * FDIM + 4 * l) = res;
}

extern "C" void kernel_launch(void* const* d_in, const int* in_sizes, int n_in,
                              void* d_out, int out_size, void* d_ws, size_t ws_size,
                              hipStream_t stream) {
    const float* x    = (const float*)d_in[0];
    const float* adj  = (const float*)d_in[1];
    const float* W_w  = (const float*)d_in[2];
    const float* W_b  = (const float*)d_in[3];
    // d_in[4] = A  (dead code in reference, unused)
    const float* gw   = (const float*)d_in[5];
    const float* gb   = (const float*)d_in[6];
    float* out = (float*)d_out;
    __bf16* h = (__bf16*)d_ws;   // 8192*256 bf16 = 4 MB scratch

    h_gemm_mfma<<<dim3(256), dim3(256), 0, stream>>>(x, W_w, W_b, h);
    agg_gate<<<dim3(M_TOT / 4), dim3(256), 0, stream>>>(adj, x, h, gw, gb, out);
}

// Round 6
// 102.747 us; speedup vs baseline: 1.0075x; 1.0041x over previous
//
#include <hip/hip_runtime.h>
#include <math.h>

// Problem: B=16, N=512, F=256.
// Live computation only (attention matrix is dead code in the reference):
//   h       = x @ W_w^T + W_b                      [B,N,F]   (bf16 MFMA)
//   h_prime = leaky_relu(adj @ h, 0.2)             [B,N,F]   (sparse gather, h bf16)
//   g       = [x, h_prime] @ gate_w^T + gate_b     [B,N,1]
//   out     = sigmoid(g)*x + (1-sigmoid(g))*h_prime
//
// Measurement model (R6-R8 rocprof): total includes ~90 us harness reset;
// visible 256 MB fills vary 44.0-47.3 us run-to-run => total noise +-2-3 us.
// R5/R7/R8 all measured 101.6-103.5 (not attributable). Controllable budget
// ~12 us across both kernels.
// R9: k1 occupancy fix. R5/R7 ran 256 blocks = 1 wave/SIMD, so k1's global
// A-load latency was hidden only by static scheduling (VGPR-capped). Now
// BM=64/BN=64 -> 512 blocks = 2 blocks/CU = 8 waves/CU; same barrier-free
// structure (W staged once, 1 barrier, A direct-from-global), per-wave VGPR
// ~60 so TLP does the hiding. k2 stays R8 wave-per-row.
// R10: resubmit of R9 unchanged (acquisition timeout; R9 never measured).
// Decision rule: if R9 lands within 101-104 again => controllable budget is
// at the measurement floor; declare roofline with arithmetic.

#define BATCH 16
#define NNODE 512
#define FDIM  256
#define M_TOT (BATCH * NNODE)   // 8192

typedef __bf16 bf16x8 __attribute__((ext_vector_type(8)));
typedef __bf16 bf16x4 __attribute__((ext_vector_type(4)));
typedef float  f32x4  __attribute__((ext_vector_type(4)));

static __device__ __forceinline__ bf16x4 cvt4(float4 v) {
    bf16x4 r;
    r.x = (__bf16)v.x; r.y = (__bf16)v.y; r.z = (__bf16)v.z; r.w = (__bf16)v.w;
    return r;
}

static __device__ __forceinline__ bf16x8 cvt8(float4 lo, float4 hi) {
    bf16x8 r;
    r[0] = (__bf16)lo.x; r[1] = (__bf16)lo.y; r[2] = (__bf16)lo.z; r[3] = (__bf16)lo.w;
    r[4] = (__bf16)hi.x; r[5] = (__bf16)hi.y; r[6] = (__bf16)hi.z; r[7] = (__bf16)hi.w;
    return r;
}

// ---------------- Kernel 1: h = x @ W^T + bias  (bf16 MFMA) ----------------
// M=8192, N=256, K=256. BM=64, BN=64 -> 512 blocks = 2 blocks/CU (8 waves/CU).
// Per block: stage W n-panel (64x256 -> 33.8 KB bf16 LDS) once, ONE barrier,
// then 8 fully-unrolled k-steps of {direct-global A loads + LDS B reads +
// 4 MFMA per wave}. Wave w owns m-rows [m0+16w, +16) x all 64 n-cols.
// BSTR=264 bf16 = 132 dwords == 4 mod 32 (same bank-residue as measured
// conflict-free ASTR=72).
#define BSTR 264

__global__ __launch_bounds__(256) void h_gemm_mfma(const float* __restrict__ x,
                                                   const float* __restrict__ W,
                                                   const float* __restrict__ bias,
                                                   __bf16* __restrict__ h) {
    __shared__ __bf16 Bs[64 * BSTR];   // 33792 B

    const int t    = threadIdx.x;
    const int wave = t >> 6;
    const int lane = t & 63;
    const int ln   = lane & 15;
    const int quad = lane >> 4;

    // XCD swizzle (8 XCDs, 512 blocks, bijective): xcd = bid&7 owns 16
    // contiguous m-tiles x 4 n-tiles, so blocks re-reading the same x rows
    // and W panels share one L2.
    const int xcd    = (int)(blockIdx.x & 7);
    const int idx    = (int)(blockIdx.x >> 3);   // 0..63
    const int mlocal = idx >> 2;                 // 0..15
    const int m0     = (xcd * 16 + mlocal) * 64;
    const int n0     = (idx & 3) * 64;

    // ---- One-time stage of W panel rows n0..n0+63, all K, f32 -> bf16 ----
    {
        const int r = t >> 2;                    // 0..63
        const int q = t & 3;                     // col quarter (64 cols)
        const float* wp = W + (size_t)(n0 + r) * FDIM + q * 64;
        __bf16* dst = &Bs[r * BSTR + q * 64];
#pragma unroll
        for (int i = 0; i < 16; i++) {
            float4 v = *(const float4*)(wp + 4 * i);
            *(bf16x4*)(dst + 4 * i) = cvt4(v);
        }
    }
    __syncthreads();   // the ONLY barrier

    // A rows owned by this wave (MFMA A-layout: lane ln -> row, quad -> k*8).
    const int rowA = m0 + wave * 16 + ln;
    const float* xa = x + (size_t)rowA * FDIM + quad * 8;

    f32x4 acc[4] = {};

#pragma unroll
    for (int ks = 0; ks < FDIM; ks += 32) {
        float4 al = *(const float4*)(xa + ks);
        float4 ah = *(const float4*)(xa + ks + 4);
        bf16x8 a = cvt8(al, ah);

        const int kb = ks + quad * 8;
        bf16x8 b0 = *(const bf16x8*)&Bs[(0  + ln) * BSTR + kb];
        bf16x8 b1 = *(const bf16x8*)&Bs[(16 + ln) * BSTR + kb];
        bf16x8 b2 = *(const bf16x8*)&Bs[(32 + ln) * BSTR + kb];
        bf16x8 b3 = *(const bf16x8*)&Bs[(48 + ln) * BSTR + kb];

        acc[0] = __builtin_amdgcn_mfma_f32_16x16x32_bf16(a, b0, acc[0], 0, 0, 0);
        acc[1] = __builtin_amdgcn_mfma_f32_16x16x32_bf16(a, b1, acc[1], 0, 0, 0);
        acc[2] = __builtin_amdgcn_mfma_f32_16x16x32_bf16(a, b2, acc[2], 0, 0, 0);
        acc[3] = __builtin_amdgcn_mfma_f32_16x16x32_bf16(a, b3, acc[3], 0, 0, 0);
    }

    // Epilogue: D[row][col], col = lane&15, row = quad*4 + reg. Add bias, store bf16.
    const int mbase = m0 + wave * 16 + quad * 4;
#pragma unroll
    for (int j = 0; j < 4; j++) {
        const int gn = n0 + j * 16 + ln;
        const float bv = bias[gn];
        f32x4 c = acc[j];
#pragma unroll
        for (int r = 0; r < 4; r++) {
            h[(size_t)(mbase + r) * FDIM + gn] = (__bf16)(c[r] + bv);
        }
    }
}

// ---------------- Kernel 2: sparse aggregate + gate + blend ----------------
// R8: one WAVE per output row (b,i); 2048 blocks x 256 thr = 4 independent
// waves/block (32 waves/CU). No LDS, no __syncthreads, no atomics.
// Per wave: lane l owns cols 4l..4l+3.
//  1. adj row: 4x float2 per lane (coalesced 512 B/round).
//  2. nonzeros via __ballot -> wave-uniform 64-bit masks; ctz bit-scan gives
//     wave-uniform j -> scalar-addressed coalesced 512 B gather of h[j].
//  3. f32 accumulate, leaky_relu, gate partial over own 4 cols,
//     shfl_xor butterfly (all lanes get g), sigmoid, float4 store.
__global__ __launch_bounds__(256) void agg_gate(const float* __restrict__ adj,
                                                const float* __restrict__ x,
                                                const __bf16* __restrict__ h,
                                                const float* __restrict__ gw,
                                                const float* __restrict__ gb,
                                                float* __restrict__ out) {
    const int t  = threadIdx.x;
    const int w  = t >> 6;
    const int l  = t & 63;
    const int bi = (int)blockIdx.x * 4 + w;   // 0..8191
    const int b  = bi >> 9;

    // Load adj row: entries r*128 + 2l, 2l+1 for r = 0..3.
    const float* arow = adj + (size_t)bi * NNODE;
    float2 a0 = *(const float2*)(arow + 0 * 128 + 2 * l);
    float2 a1 = *(const float2*)(arow + 1 * 128 + 2 * l);
    float2 a2 = *(const float2*)(arow + 2 * 128 + 2 * l);
    float2 a3 = *(const float2*)(arow + 3 * 128 + 2 * l);

    const float4 xv = *(const float4*)(x + (size_t)bi * FDIM + 4 * l);

    // Wave-uniform neighbor masks (even/odd slots per round).
    unsigned long long me[4], mo[4];
    me[0] = __ballot(a0.x != 0.0f); mo[0] = __ballot(a0.y != 0.0f);
    me[1] = __ballot(a1.x != 0.0f); mo[1] = __ballot(a1.y != 0.0f);
    me[2] = __ballot(a2.x != 0.0f); mo[2] = __ballot(a2.y != 0.0f);
    me[3] = __ballot(a3.x != 0.0f); mo[3] = __ballot(a3.y != 0.0f);

    const __bf16* hb = h + (size_t)b * NNODE * FDIM + 4 * l;  // lane's 4 cols

    float4 s = {0.f, 0.f, 0.f, 0.f};
#pragma unroll
    for (int r = 0; r < 4; r++) {
        unsigned long long m0 = me[r];
        while (m0) {
            const int bp = __builtin_ctzll(m0); m0 &= m0 - 1;
            const int j  = r * 128 + 2 * bp;          // wave-uniform
            bf16x4 v = *(const bf16x4*)(hb + (size_t)j * FDIM);
            s.x += (float)v.x; s.y += (float)v.y; s.z += (float)v.z; s.w += (float)v.w;
        }
        unsigned long long m1 = mo[r];
        while (m1) {
            const int bp = __builtin_ctzll(m1); m1 &= m1 - 1;
            const int j  = r * 128 + 2 * bp + 1;      // wave-uniform
            bf16x4 v = *(const bf16x4*)(hb + (size_t)j * FDIM);
            s.x += (float)v.x; s.y += (float)v.y; s.z += (float)v.z; s.w += (float)v.w;
        }
    }

    // leaky_relu(0.2)
    float4 hp;
    hp.x = (s.x > 0.0f) ? s.x : 0.2f * s.x;
    hp.y = (s.y > 0.0f) ? s.y : 0.2f * s.y;
    hp.z = (s.z > 0.0f) ? s.z : 0.2f * s.z;
    hp.w = (s.w > 0.0f) ? s.w : 0.2f * s.w;

    // gate: g = x . gw[0:256] + hp . gw[256:512] + gb (per-lane 4-col partial)
    const float4 g0 = *(const float4*)(gw + 4 * l);
    const float4 g1 = *(const float4*)(gw + FDIM + 4 * l);
    float partial = xv.x * g0.x + xv.y * g0.y + xv.z * g0.z + xv.w * g0.w
                  + hp.x * g1.x + hp.y * g1.y + hp.z * g1.z + hp.w * g1.w;
#pragma unroll
    for (int off = 32; off > 0; off >>= 1) partial += __shfl_xor(partial, off);

    const float g = partial + gb[0];
    const float c = 1.0f / (1.0f + expf(-g));

    float4 res;
    res.x = c * xv.x + (1.0f - c) * hp.x;
    res.y = c * xv.y + (1.0f - c) * hp.y;
    res.z = c * xv.z + (1.0f - c) * hp.z;
    res.w = c * xv.w + (1.0f - c) * hp.w;
    *(float4*)(out + (size_t)bi * FDIM + 4 * l) = res;
}

extern "C" void kernel_launch(void* const* d_in, const int* in_sizes, int n_in,
                              void* d_out, int out_size, void* d_ws, size_t ws_size,
                              hipStream_t stream) {
    const float* x    = (const float*)d_in[0];
    const float* adj  = (const float*)d_in[1];
    const float* W_w  = (const float*)d_in[2];
    const float* W_b  = (const float*)d_in[3];
    // d_in[4] = A  (dead code in reference, unused)
    const float* gw   = (const float*)d_in[5];
    const float* gb   = (const float*)d_in[6];
    float* out = (float*)d_out;
    __bf16* h = (__bf16*)d_ws;   // 8192*256 bf16 = 4 MB scratch

    h_gemm_mfma<<<dim3(512), dim3(256), 0, stream>>>(x, W_w, W_b, h);
    agg_gate<<<dim3(M_TOT / 4), dim3(256), 0, stream>>>(adj, x, h, gw, gb, out);
}